// Round 1
// baseline (1637.450 us; speedup 1.0000x reference)
//
#include <hip/hip_runtime.h>

// Problem constants
#define T_LEN 1024
#define B_SZ 4
#define E_DIM 1024
#define H_NUM 16
#define D_DIM 64
#define M_ROWS 4096            // T*B
#define PROJ_ELEMS 4194304     // 4096*1024 = BH*T*D
#define AW_ELEMS 4194304       // B*T*S

// ---------------------------------------------------------------------------
// Tiled fp32 GEMM: C[m,n] = sum_e X[m,e]*W[n,e] + bias[n], optionally scaled.
// MODE 0: QKV projection (grid.z selects q/k/v), output head-major [BH,T,D]
// MODE 1: out-projection, output natural [m, n]
// Tile 128x128, BK=32, 256 threads, 8x8 micro-tile.
// ---------------------------------------------------------------------------
template<int MODE>
__global__ __launch_bounds__(256)
void gemm_xwt(const float* __restrict__ Xq, const float* __restrict__ Xk,
              const float* __restrict__ Xv, const float* __restrict__ W0,
              const float* __restrict__ bias0, float* __restrict__ out0)
{
    __shared__ float Xs[32][132];
    __shared__ float Ws[32][132];

    const int tid = threadIdx.x;
    const int z = (MODE == 0) ? blockIdx.z : 0;
    const float* X = (MODE == 0) ? (z == 0 ? Xq : (z == 1 ? Xk : Xv)) : Xq;
    const float* W = (MODE == 0) ? (W0 + (size_t)z * E_DIM * E_DIM) : W0;
    const float* bias = (MODE == 0) ? (bias0 + z * E_DIM) : bias0;
    const float scale = (MODE == 0 && z == 0) ? 0.125f : 1.0f;   // D^-0.5
    float* out = (MODE == 0) ? (out0 + (size_t)z * PROJ_ELEMS) : out0;

    const int m0 = blockIdx.y * 128;
    const int n0 = blockIdx.x * 128;
    const int ty = tid >> 4, tx = tid & 15;

    float acc[8][8];
    #pragma unroll
    for (int u = 0; u < 8; ++u)
        #pragma unroll
        for (int v = 0; v < 8; ++v) acc[u][v] = 0.f;

    for (int k0 = 0; k0 < E_DIM; k0 += 32) {
        #pragma unroll
        for (int i = 0; i < 4; ++i) {
            int lin = tid + i * 256;        // 0..1023
            int r = lin >> 3;               // 0..127
            int c4 = lin & 7;               // 0..7
            float4 xv = *(const float4*)&X[(size_t)(m0 + r) * E_DIM + k0 + c4 * 4];
            Xs[c4*4+0][r] = xv.x; Xs[c4*4+1][r] = xv.y;
            Xs[c4*4+2][r] = xv.z; Xs[c4*4+3][r] = xv.w;
            float4 wv = *(const float4*)&W[(size_t)(n0 + r) * E_DIM + k0 + c4 * 4];
            Ws[c4*4+0][r] = wv.x; Ws[c4*4+1][r] = wv.y;
            Ws[c4*4+2][r] = wv.z; Ws[c4*4+3][r] = wv.w;
        }
        __syncthreads();
        #pragma unroll 8
        for (int kk = 0; kk < 32; ++kk) {
            float a[8], b[8];
            *(float4*)&a[0] = *(const float4*)&Xs[kk][ty*8];
            *(float4*)&a[4] = *(const float4*)&Xs[kk][ty*8+4];
            *(float4*)&b[0] = *(const float4*)&Ws[kk][tx*8];
            *(float4*)&b[4] = *(const float4*)&Ws[kk][tx*8+4];
            #pragma unroll
            for (int u = 0; u < 8; ++u)
                #pragma unroll
                for (int v = 0; v < 8; ++v)
                    acc[u][v] += a[u] * b[v];
        }
        __syncthreads();
    }

    #pragma unroll
    for (int u = 0; u < 8; ++u) {
        int m = m0 + ty * 8 + u;
        #pragma unroll
        for (int v = 0; v < 8; ++v) {
            int n = n0 + tx * 8 + v;
            float val = (acc[u][v] + bias[n]) * scale;
            if (MODE == 0) {
                int t = m >> 2, bb = m & 3, hh = n >> 6, dd = n & 63;
                out[(size_t)((bb * H_NUM + hh) * T_LEN + t) * D_DIM + dd] = val;
            } else {
                out[(size_t)m * E_DIM + n] = val;
            }
        }
    }
}

// ---------------------------------------------------------------------------
// Attention: block = (b, head-group of 4, 16 q-rows). 256 threads.
// Logit mapping: wave tg owns rows tg*4+i; lane sgg owns s = c*128 + sgg(+64).
// P kept in registers (64/thread); aw accumulated in registers over 4 heads.
// PV mapping: thread (tl = tid>>4, d4 = tid&15) computes out[t0+tl][d4*4..+3].
// ---------------------------------------------------------------------------
__global__ __launch_bounds__(256)
void attn_kernel(const float* __restrict__ ws_q, const float* __restrict__ ws_k,
                 const float* __restrict__ ws_v, float* __restrict__ attn_pre,
                 float* __restrict__ aw_part)
{
    __shared__ float q_s[16][68];
    __shared__ float kv_s[128][68];
    __shared__ float p_s[16][132];

    const int tid = threadIdx.x;
    const int t0 = blockIdx.x * 16;
    const int hg = blockIdx.y;
    const int b  = blockIdx.z;

    const int tg  = tid >> 6;   // wave id: rows tg*4 .. tg*4+3
    const int sgg = tid & 63;   // lane
    const int tl  = tid >> 4;   // PV row
    const int d4  = tid & 15;   // PV col group

    float aw[4][16];
    #pragma unroll
    for (int i = 0; i < 4; ++i)
        #pragma unroll
        for (int j = 0; j < 16; ++j) aw[i][j] = 0.f;

    for (int hh = 0; hh < 4; ++hh) {
        const int h = hg * 4 + hh;
        const int bh = b * H_NUM + h;
        const float* qh = ws_q + (size_t)bh * (T_LEN * D_DIM);
        const float* kh = ws_k + (size_t)bh * (T_LEN * D_DIM);
        const float* vh = ws_v + (size_t)bh * (T_LEN * D_DIM);

        // stage q tile [16][64]
        {
            float4 qv = *(const float4*)&qh[(size_t)(t0 + tl) * D_DIM + d4 * 4];
            *(float4*)&q_s[tl][d4 * 4] = qv;
        }

        float l[4][16];

        // ---- logits: 8 chunks of 128 s ----
        #pragma unroll
        for (int c = 0; c < 8; ++c) {
            __syncthreads();
            #pragma unroll
            for (int i = 0; i < 8; ++i) {
                int lin = tid + i * 256;
                int r = lin >> 4, c4 = lin & 15;
                *(float4*)&kv_s[r][c4 * 4] =
                    *(const float4*)&kh[(size_t)(c * 128 + r) * D_DIM + c4 * 4];
            }
            __syncthreads();
            float a0[4] = {0.f, 0.f, 0.f, 0.f};
            float a1[4] = {0.f, 0.f, 0.f, 0.f};
            #pragma unroll 4
            for (int dd = 0; dd < 16; ++dd) {
                float4 k0 = *(const float4*)&kv_s[sgg][dd * 4];
                float4 k1 = *(const float4*)&kv_s[sgg + 64][dd * 4];
                #pragma unroll
                for (int i = 0; i < 4; ++i) {
                    float4 qv = *(const float4*)&q_s[tg * 4 + i][dd * 4];
                    a0[i] += qv.x*k0.x + qv.y*k0.y + qv.z*k0.z + qv.w*k0.w;
                    a1[i] += qv.x*k1.x + qv.y*k1.y + qv.z*k1.z + qv.w*k1.w;
                }
            }
            #pragma unroll
            for (int i = 0; i < 4; ++i) { l[i][c*2] = a0[i]; l[i][c*2+1] = a1[i]; }
        }

        // ---- softmax (wave-level reduce; one wave = 4 rows) + aw accumulate ----
        #pragma unroll
        for (int i = 0; i < 4; ++i) {
            float m = l[i][0];
            #pragma unroll
            for (int j = 1; j < 16; ++j) m = fmaxf(m, l[i][j]);
            #pragma unroll
            for (int off = 32; off > 0; off >>= 1) m = fmaxf(m, __shfl_xor(m, off));
            float s = 0.f;
            #pragma unroll
            for (int j = 0; j < 16; ++j) { float e = __expf(l[i][j] - m); l[i][j] = e; s += e; }
            #pragma unroll
            for (int off = 32; off > 0; off >>= 1) s += __shfl_xor(s, off);
            float inv = 1.0f / s;
            #pragma unroll
            for (int j = 0; j < 16; ++j) { l[i][j] *= inv; aw[i][j] += l[i][j]; }
        }

        // ---- PV: 8 chunks of 128 s ----
        float4 oacc = make_float4(0.f, 0.f, 0.f, 0.f);
        #pragma unroll
        for (int c = 0; c < 8; ++c) {
            __syncthreads();
            #pragma unroll
            for (int i = 0; i < 8; ++i) {
                int lin = tid + i * 256;
                int r = lin >> 4, c4 = lin & 15;
                *(float4*)&kv_s[r][c4 * 4] =
                    *(const float4*)&vh[(size_t)(c * 128 + r) * D_DIM + c4 * 4];
            }
            #pragma unroll
            for (int i = 0; i < 4; ++i) {
                p_s[tg * 4 + i][sgg]      = l[i][c*2];
                p_s[tg * 4 + i][sgg + 64] = l[i][c*2+1];
            }
            __syncthreads();
            #pragma unroll 4
            for (int s4 = 0; s4 < 32; ++s4) {
                float4 p4 = *(const float4*)&p_s[tl][s4 * 4];
                float4 v0 = *(const float4*)&kv_s[s4*4+0][d4*4];
                float4 v1 = *(const float4*)&kv_s[s4*4+1][d4*4];
                float4 v2 = *(const float4*)&kv_s[s4*4+2][d4*4];
                float4 v3 = *(const float4*)&kv_s[s4*4+3][d4*4];
                oacc.x += p4.x*v0.x + p4.y*v1.x + p4.z*v2.x + p4.w*v3.x;
                oacc.y += p4.x*v0.y + p4.y*v1.y + p4.z*v2.y + p4.w*v3.y;
                oacc.z += p4.x*v0.z + p4.y*v1.z + p4.z*v2.z + p4.w*v3.z;
                oacc.w += p4.x*v0.w + p4.y*v1.w + p4.z*v2.w + p4.w*v3.w;
            }
        }
        // attn_pre row m = t*B + b, col n = h*64 + d
        *(float4*)&attn_pre[(size_t)((t0 + tl) * B_SZ + b) * E_DIM + h * D_DIM + d4 * 4] = oacc;
    }

    // ---- aw partial write (one per head-group; fully coalesced) ----
    const size_t aw_base = (size_t)hg * AW_ELEMS + (size_t)b * (T_LEN * T_LEN);
    #pragma unroll
    for (int i = 0; i < 4; ++i) {
        int t = t0 + tg * 4 + i;
        #pragma unroll
        for (int c = 0; c < 8; ++c) {
            aw_part[aw_base + (size_t)t * T_LEN + c * 128 + sgg]      = aw[i][c*2];
            aw_part[aw_base + (size_t)t * T_LEN + c * 128 + 64 + sgg] = aw[i][c*2+1];
        }
    }
}

// ---------------------------------------------------------------------------
// aw = (p0+p1+p2+p3) / 16
// ---------------------------------------------------------------------------
__global__ __launch_bounds__(256)
void aw_reduce(const float* __restrict__ p, float* __restrict__ out2)
{
    size_t i = ((size_t)blockIdx.x * 256 + threadIdx.x) * 4;
    float4 a = *(const float4*)(p + i);
    float4 b = *(const float4*)(p + (size_t)AW_ELEMS + i);
    float4 c = *(const float4*)(p + (size_t)2 * AW_ELEMS + i);
    float4 d = *(const float4*)(p + (size_t)3 * AW_ELEMS + i);
    float4 r;
    r.x = (a.x + b.x + c.x + d.x) * 0.0625f;
    r.y = (a.y + b.y + c.y + d.y) * 0.0625f;
    r.z = (a.z + b.z + c.z + d.z) * 0.0625f;
    r.w = (a.w + b.w + c.w + d.w) * 0.0625f;
    *(float4*)(out2 + i) = r;
}

extern "C" void kernel_launch(void* const* d_in, const int* in_sizes, int n_in,
                              void* d_out, int out_size, void* d_ws, size_t ws_size,
                              hipStream_t stream) {
    const float* query = (const float*)d_in[0];
    const float* key   = (const float*)d_in[1];
    const float* value = (const float*)d_in[2];
    const float* ipw   = (const float*)d_in[3];
    const float* ipb   = (const float*)d_in[4];
    const float* opw   = (const float*)d_in[5];
    const float* opb   = (const float*)d_in[6];
    // co_* / h_* weights (d_in[7..11]) are mathematically dead:
    // softmax over a size-1 axis == 1.0 exactly, so the gates are identity.

    float* out = (float*)d_out;
    float* ws  = (float*)d_ws;

    float* qh       = ws;                      // [BH,T,D]  4M floats
    float* kh       = ws + (size_t)PROJ_ELEMS;         // 4M
    float* vh       = ws + (size_t)2 * PROJ_ELEMS;     // 4M
    float* attn_pre = ws + (size_t)3 * PROJ_ELEMS;     // 4M  [m=t*B+b][E]
    float* aw_part  = ws + (size_t)4 * PROJ_ELEMS;     // 4 x 4M

    // QKV projection (+bias, q scaled), re-layout to head-major
    gemm_xwt<0><<<dim3(8, 32, 3), 256, 0, stream>>>(query, key, value, ipw, ipb, qh);
    // attention + aw partials
    attn_kernel<<<dim3(64, 4, 4), 256, 0, stream>>>(qh, kh, vh, attn_pre, aw_part);
    // out projection -> first output
    gemm_xwt<1><<<dim3(8, 32, 1), 256, 0, stream>>>(attn_pre, nullptr, nullptr, opw, opb, out);
    // aw mean over heads -> second output
    aw_reduce<<<4096, 256, 0, stream>>>(aw_part, out + (size_t)AW_ELEMS);
}

// Round 2
// 687.997 us; speedup vs baseline: 2.3800x; 2.3800x over previous
//
#include <hip/hip_runtime.h>

typedef __attribute__((ext_vector_type(8))) short s8v;
typedef __attribute__((ext_vector_type(4))) float f4v;
typedef unsigned short u16;

#define T_LEN 1024
#define B_SZ 4
#define H_NUM 16
#define D_DIM 64
#define E_DIM 1024

#define MBY ((size_t)1<<20)

// ---- workspace layout (bytes), total exactly 128MB, phase-overlaid ----
// phase 1 (splits+QKV gemm):  x splits at z*16MB (hi, lo=+8MB); ipw 64/70MB; opw 76/78MB
// phase 2 (attention):        aw partials at 0/16MB; v_t at 32/40MB; attn32 at 48MB
// phase 3 (out-proj):         attn_hi/lo at 80/88MB (over dead q)
#define OFF_X(z)     ((size_t)(z)*16*MBY)
#define OFF_AW(g)    ((size_t)(g)*16*MBY)
#define OFF_VT_HI    (32*MBY)
#define OFF_VT_LO    (40*MBY)
#define OFF_ATTN32   (48*MBY)
#define OFF_IPW_HI   (64*MBY)
#define OFF_IPW_LO   (70*MBY)
#define OFF_OPW_HI   (76*MBY)
#define OFF_OPW_LO   (78*MBY)
#define OFF_QKV(z)   ((80*MBY) + (size_t)(z)*16*MBY)   // hi; lo = +8MB (4M elems)
#define OFF_ATTN_HI  (80*MBY)
#define OFF_ATTN_LO  (88*MBY)

__device__ __forceinline__ u16 f2bf(float x){
    unsigned u = __float_as_uint(x);
    u += 0x7fffu + ((u>>16)&1u);          // RNE
    return (u16)(u>>16);
}
__device__ __forceinline__ float bf2f(u16 h){
    return __uint_as_float(((unsigned)h)<<16);
}
__device__ __forceinline__ void glds16(const void* g, void* l){
    __builtin_amdgcn_global_load_lds((const __attribute__((address_space(1))) unsigned*)g,
                                     (__attribute__((address_space(3))) unsigned*)l, 16, 0, 0);
}
#define MFMA_BF16(a,b,c) __builtin_amdgcn_mfma_f32_16x16x32_bf16((a),(b),(c),0,0,0)

// ---------------------------------------------------------------------------
// fp32 -> (hi, lo) bf16 split, 8 elems/thread
// ---------------------------------------------------------------------------
__global__ __launch_bounds__(256) void split_bf16(const float* __restrict__ src,
        u16* __restrict__ hi, u16* __restrict__ lo)
{
    size_t i = ((size_t)blockIdx.x*256 + threadIdx.x)*8;
    float4 a = *(const float4*)(src + i);
    float4 b = *(const float4*)(src + i + 4);
    float v[8] = {a.x,a.y,a.z,a.w,b.x,b.y,b.z,b.w};
    s8v hv, lv;
    #pragma unroll
    for (int j=0;j<8;++j){
        u16 h = f2bf(v[j]);
        hv[j] = (short)h;
        lv[j] = (short)f2bf(v[j] - bf2f(h));
    }
    *(s8v*)(hi+i) = hv;
    *(s8v*)(lo+i) = lv;
}

// ---------------------------------------------------------------------------
// Split-bf16 MFMA GEMM: C[m,n] = sum_k A[m,k]*W[n,k] (+bias)*scale
// 128x128 tile, BK=32, 256 thr = 4 waves (2x2), each wave 64x64 (4x4 frags).
// MODE 0: QKV (z selects), out = hi/lo bf16 head-major [bh][t][d]
// MODE 1: out-proj, out = fp32 [m][n]
// LDS tiles [128][32] bf16 with unit-XOR swizzle (u ^= row&3) -> ~2-way reads.
// ---------------------------------------------------------------------------
template<int MODE>
__global__ __launch_bounds__(256) void gemm_split(char* __restrict__ wsb,
        const float* __restrict__ bias0, float* __restrict__ out32)
{
    __shared__ u16 Ah[4096], Al[4096], Bh[4096], Bl[4096];
    const int tid = threadIdx.x;
    const int wv = tid>>6, l = tid&63;
    const int lr = l&15, lg = l>>4;
    const int z = (MODE==0)? blockIdx.z : 0;

    const u16 *Ahi,*Alo,*Whi,*Wlo;
    const float* bias; float scale;
    u16 *outH = nullptr, *outL = nullptr;
    if (MODE==0){
        Ahi = (const u16*)(wsb + OFF_X(z));
        Alo = Ahi + 4*MBY;
        Whi = (const u16*)(wsb + OFF_IPW_HI) + (size_t)z*E_DIM*E_DIM;
        Wlo = (const u16*)(wsb + OFF_IPW_LO) + (size_t)z*E_DIM*E_DIM;
        bias = bias0 + z*E_DIM;
        scale = (z==0)? 0.125f : 1.0f;     // D^-0.5 baked into q
        outH = (u16*)(wsb + OFF_QKV(z));
        outL = outH + 4*MBY;
    } else {
        Ahi = (const u16*)(wsb + OFF_ATTN_HI);
        Alo = (const u16*)(wsb + OFF_ATTN_LO);
        Whi = (const u16*)(wsb + OFF_OPW_HI);
        Wlo = (const u16*)(wsb + OFF_OPW_LO);
        bias = bias0; scale = 1.0f;
    }

    const int m0 = blockIdx.y*128, n0 = blockIdx.x*128;

    f4v acc[4][4];
    #pragma unroll
    for (int i=0;i<4;++i)
        #pragma unroll
        for (int j=0;j<4;++j) acc[i][j] = (f4v){0.f,0.f,0.f,0.f};

    for (int k0=0; k0<E_DIM; k0+=32){
        #pragma unroll
        for (int i=0;i<2;++i){
            int ci  = i*4 + wv;                 // 1KB chunk id, wave-uniform
            int row = ci*16 + (l>>2);
            int u   = (l&3) ^ ((l>>2)&3);       // swizzled 8-elem unit
            size_t aoff = (size_t)(m0+row)*E_DIM + k0 + u*8;
            size_t boff = (size_t)(n0+row)*E_DIM + k0 + u*8;
            glds16(Ahi+aoff, &Ah[ci*512]);
            glds16(Alo+aoff, &Al[ci*512]);
            glds16(Whi+boff, &Bh[ci*512]);
            glds16(Wlo+boff, &Bl[ci*512]);
        }
        __syncthreads();                        // implicit vmcnt(0) drain
        s8v ah[4],al[4],bh[4],bl[4];
        #pragma unroll
        for (int mi=0;mi<4;++mi){
            int row = (wv>>1)*64 + mi*16 + lr;
            int off = row*32 + ((lg ^ (row&3))<<3);
            ah[mi] = *(const s8v*)&Ah[off];
            al[mi] = *(const s8v*)&Al[off];
        }
        #pragma unroll
        for (int ni=0;ni<4;++ni){
            int row = (wv&1)*64 + ni*16 + lr;
            int off = row*32 + ((lg ^ (row&3))<<3);
            bh[ni] = *(const s8v*)&Bh[off];
            bl[ni] = *(const s8v*)&Bl[off];
        }
        #pragma unroll
        for (int mi=0;mi<4;++mi)
            #pragma unroll
            for (int ni=0;ni<4;++ni){
                acc[mi][ni] = MFMA_BF16(ah[mi], bh[ni], acc[mi][ni]);
                acc[mi][ni] = MFMA_BF16(ah[mi], bl[ni], acc[mi][ni]);
                acc[mi][ni] = MFMA_BF16(al[mi], bh[ni], acc[mi][ni]);
            }
        __syncthreads();
    }

    #pragma unroll
    for (int mi=0;mi<4;++mi){
        #pragma unroll
        for (int ni=0;ni<4;++ni){
            int n = n0 + (wv&1)*64 + ni*16 + lr;
            float bn = bias[n];
            #pragma unroll
            for (int r=0;r<4;++r){
                int m = m0 + (wv>>1)*64 + mi*16 + lg*4 + r;   // D: row=(l>>4)*4+reg
                float val = (acc[mi][ni][r] + bn)*scale;
                if (MODE==0){
                    int t = m>>2, bb = m&3, hh2 = n>>6, dd = n&63;
                    size_t idx = ((size_t)(bb*H_NUM+hh2)*T_LEN + t)*D_DIM + dd;
                    u16 hb_ = f2bf(val);
                    outH[idx] = hb_;
                    outL[idx] = f2bf(val - bf2f(hb_));
                } else {
                    out32[(size_t)m*E_DIM + n] = val;
                }
            }
        }
    }
}

// ---------------------------------------------------------------------------
// v (head-major [bh][s][d], hi/lo bf16) -> v_t ([bh][d][s], hi/lo bf16)
// ---------------------------------------------------------------------------
__global__ __launch_bounds__(256) void transpose_v(char* __restrict__ wsb)
{
    __shared__ u16 Th[64][72], Tl[64][72];
    const int tid = threadIdx.x;
    const int bh  = blockIdx.y;
    const int s0  = blockIdx.x*64;
    const u16* vh = (const u16*)(wsb + OFF_QKV(2));
    const u16* vl = vh + 4*MBY;
    u16* th = (u16*)(wsb + OFF_VT_HI);
    u16* tl = (u16*)(wsb + OFF_VT_LO);

    #pragma unroll
    for (int it=0; it<2; ++it){
        int u = it*256 + tid;
        int s = u>>3, c8 = u&7;
        size_t off = ((size_t)bh*T_LEN + s0+s)*D_DIM + c8*8;
        s8v a  = *(const s8v*)&vh[off];
        s8v b_ = *(const s8v*)&vl[off];
        #pragma unroll
        for (int j=0;j<8;++j){
            Th[c8*8+j][s] = (u16)a[j];
            Tl[c8*8+j][s] = (u16)b_[j];
        }
    }
    __syncthreads();
    #pragma unroll
    for (int it=0; it<2; ++it){
        int u = it*256 + tid;
        int d = u>>3, sc = u&7;
        s8v rh = *(const s8v*)&Th[d][sc*8];
        s8v rl = *(const s8v*)&Tl[d][sc*8];
        size_t off = ((size_t)bh*D_DIM + d)*T_LEN + s0 + sc*8;
        *(s8v*)&th[off] = rh;
        *(s8v*)&tl[off] = rl;
    }
}

// ---------------------------------------------------------------------------
// MFMA attention. Block = (b, head-group of 8, 16 q-rows), 256 thr = 4 waves.
// Wave wv owns s-slice wv*16 within each 64-chunk (QK^T) and d-slice wv*16 (PV).
// S/P in 64 acc VGPRs; P bounced via XOR-swizzled double-buffered LDS for PV
// A-frags; K/V/Q frags read straight from global (L2-resident, 64B sectors).
// aw accumulated in regs over 8 heads -> 2 partial buffers.
// ---------------------------------------------------------------------------
__global__ __launch_bounds__(256) void attn_mfma(char* __restrict__ wsb)
{
    __shared__ u16 Ph[2][1024], Pl[2][1024];     // [16 rows][64 s] swizzled
    __shared__ float redM[16][4], redS[16][4];

    const int tid = threadIdx.x;
    const int wv = tid>>6, l = tid&63, lr = l&15, lg = l>>4;
    const int t0 = blockIdx.x*16;
    const int hg = blockIdx.y;                   // 0..1
    const int b  = blockIdx.z;

    const u16* qhi = (const u16*)(wsb + OFF_QKV(0));
    const u16* qlo = qhi + 4*MBY;
    const u16* khi = (const u16*)(wsb + OFF_QKV(1));
    const u16* klo = khi + 4*MBY;
    const u16* vth = (const u16*)(wsb + OFF_VT_HI);
    const u16* vtl = (const u16*)(wsb + OFF_VT_LO);
    float* attn32 = (float*)(wsb + OFF_ATTN32);
    float* awb    = (float*)(wsb + OFF_AW(hg)) + (size_t)b*T_LEN*T_LEN;

    float aw[16][4];
    #pragma unroll
    for (int c=0;c<16;++c)
        #pragma unroll
        for (int r=0;r<4;++r) aw[c][r] = 0.f;

    for (int hh=0; hh<8; ++hh){
        const int h = hg*8 + hh;
        const size_t hb = (size_t)(b*H_NUM + h)*T_LEN*D_DIM;

        // Q frags: A-layout row = l&15, k = (l>>4)*8+j (+32 per kh)
        s8v qfh[2], qfl[2];
        #pragma unroll
        for (int kh=0;kh<2;++kh){
            size_t qo = hb + (size_t)(t0+lr)*D_DIM + kh*32 + lg*8;
            qfh[kh] = *(const s8v*)&qhi[qo];
            qfl[kh] = *(const s8v*)&qlo[qo];
        }

        // ---- QK^T: S[16 rows][16 s of wave slice] per 64-chunk c ----
        f4v p[16];
        #pragma unroll
        for (int c=0;c<16;++c){
            f4v a = (f4v){0.f,0.f,0.f,0.f};
            #pragma unroll
            for (int kh=0;kh<2;++kh){
                size_t ko = hb + (size_t)(c*64 + wv*16 + lr)*D_DIM + kh*32 + lg*8;
                s8v kfh = *(const s8v*)&khi[ko];
                s8v kfl = *(const s8v*)&klo[ko];
                a = MFMA_BF16(qfh[kh], kfh, a);
                a = MFMA_BF16(qfh[kh], kfl, a);
                a = MFMA_BF16(qfl[kh], kfh, a);
            }
            p[c] = a;
        }

        // ---- softmax: row = lg*4+r, cols spread over (c, lane bits 0-3, wv)
        float Mr[4], inv[4];
        #pragma unroll
        for (int r=0;r<4;++r){
            float m_ = p[0][r];
            #pragma unroll
            for (int c=1;c<16;++c) m_ = fmaxf(m_, p[c][r]);
            m_ = fmaxf(m_, __shfl_xor(m_,1));
            m_ = fmaxf(m_, __shfl_xor(m_,2));
            m_ = fmaxf(m_, __shfl_xor(m_,4));
            m_ = fmaxf(m_, __shfl_xor(m_,8));
            if (lr==0) redM[lg*4+r][wv] = m_;
        }
        __syncthreads();
        #pragma unroll
        for (int r=0;r<4;++r){
            float4 t4 = *(const float4*)&redM[lg*4+r][0];
            Mr[r] = fmaxf(fmaxf(t4.x,t4.y), fmaxf(t4.z,t4.w));
        }
        float sm[4] = {0.f,0.f,0.f,0.f};
        #pragma unroll
        for (int c=0;c<16;++c)
            #pragma unroll
            for (int r=0;r<4;++r){
                float e = __expf(p[c][r]-Mr[r]);
                p[c][r] = e;
                sm[r] += e;
            }
        #pragma unroll
        for (int r=0;r<4;++r){
            float s_ = sm[r];
            s_ += __shfl_xor(s_,1); s_ += __shfl_xor(s_,2);
            s_ += __shfl_xor(s_,4); s_ += __shfl_xor(s_,8);
            if (lr==0) redS[lg*4+r][wv] = s_;
        }
        __syncthreads();
        #pragma unroll
        for (int r=0;r<4;++r){
            float4 t4 = *(const float4*)&redS[lg*4+r][0];
            inv[r] = 1.0f/(t4.x+t4.y+t4.z+t4.w);
        }
        #pragma unroll
        for (int c=0;c<16;++c)
            #pragma unroll
            for (int r=0;r<4;++r){
                p[c][r] *= inv[r];
                aw[c][r] += p[c][r];
            }

        // ---- PV: O[16][wv's 16 d] over all s; P via swizzled LDS bounce ----
        f4v O = (f4v){0.f,0.f,0.f,0.f};
        #pragma unroll
        for (int c=0;c<16;++c){
            const int pb = c&1;
            #pragma unroll
            for (int r=0;r<4;++r){
                int row = lg*4+r;
                int col = wv*16+lr;
                int idx = row*64 + (col ^ ((row&7)<<3));
                u16 hb_ = f2bf(p[c][r]);
                Ph[pb][idx] = hb_;
                Pl[pb][idx] = f2bf(p[c][r]-bf2f(hb_));
            }
            __syncthreads();
            #pragma unroll
            for (int kh=0;kh<2;++kh){
                int aidx = lr*64 + ((kh*32+lg*8) ^ ((lr&7)<<3));
                s8v pah = *(const s8v*)&Ph[pb][aidx];
                s8v pal = *(const s8v*)&Pl[pb][aidx];
                size_t vo = hb + (size_t)(wv*16+lr)*T_LEN + c*64 + kh*32 + lg*8;
                s8v vfh = *(const s8v*)&vth[vo];
                s8v vfl = *(const s8v*)&vtl[vo];
                O = MFMA_BF16(pah, vfh, O);
                O = MFMA_BF16(pah, vfl, O);
                O = MFMA_BF16(pal, vfh, O);
            }
        }
        #pragma unroll
        for (int r=0;r<4;++r){
            int m = (t0 + lg*4 + r)*B_SZ + b;
            int n = h*D_DIM + wv*16 + lr;
            attn32[(size_t)m*E_DIM + n] = O[r];
        }
    }

    #pragma unroll
    for (int c=0;c<16;++c)
        #pragma unroll
        for (int r=0;r<4;++r){
            int t = t0 + lg*4 + r;
            awb[(size_t)t*T_LEN + c*64 + wv*16 + lr] = aw[c][r];
        }
}

// ---------------------------------------------------------------------------
// aw = (p0+p1)/16
// ---------------------------------------------------------------------------
__global__ __launch_bounds__(256) void aw_reduce2(const float* __restrict__ p0,
        const float* __restrict__ p1, float* __restrict__ out2)
{
    size_t i = ((size_t)blockIdx.x*256 + threadIdx.x)*4;
    float4 a = *(const float4*)(p0+i);
    float4 b = *(const float4*)(p1+i);
    float4 r;
    r.x = (a.x+b.x)*0.0625f;
    r.y = (a.y+b.y)*0.0625f;
    r.z = (a.z+b.z)*0.0625f;
    r.w = (a.w+b.w)*0.0625f;
    *(float4*)(out2+i) = r;
}

extern "C" void kernel_launch(void* const* d_in, const int* in_sizes, int n_in,
                              void* d_out, int out_size, void* d_ws, size_t ws_size,
                              hipStream_t stream) {
    const float* query = (const float*)d_in[0];
    const float* key   = (const float*)d_in[1];
    const float* value = (const float*)d_in[2];
    const float* ipw   = (const float*)d_in[3];
    const float* ipb   = (const float*)d_in[4];
    const float* opw   = (const float*)d_in[5];
    const float* opb   = (const float*)d_in[6];
    // d_in[7..11] (co_*/h_*) are dead: softmax over a size-1 axis == 1 exactly.

    char* wsb = (char*)d_ws;
    float* out = (float*)d_out;

    // 1. hi/lo splits of inputs + weights
    split_bf16<<<2048,256,0,stream>>>(query, (u16*)(wsb+OFF_X(0)), (u16*)(wsb+OFF_X(0))+4*MBY);
    split_bf16<<<2048,256,0,stream>>>(key,   (u16*)(wsb+OFF_X(1)), (u16*)(wsb+OFF_X(1))+4*MBY);
    split_bf16<<<2048,256,0,stream>>>(value, (u16*)(wsb+OFF_X(2)), (u16*)(wsb+OFF_X(2))+4*MBY);
    split_bf16<<<1536,256,0,stream>>>(ipw,   (u16*)(wsb+OFF_IPW_HI), (u16*)(wsb+OFF_IPW_LO));
    split_bf16<<< 512,256,0,stream>>>(opw,   (u16*)(wsb+OFF_OPW_HI), (u16*)(wsb+OFF_OPW_LO));
    // 2. QKV projection (MFMA), head-major hi/lo out (q pre-scaled)
    gemm_split<0><<<dim3(8,32,3),256,0,stream>>>(wsb, ipb, nullptr);
    // 3. V transpose to [bh][d][s]
    transpose_v<<<dim3(16,64),256,0,stream>>>(wsb);
    // 4. attention + aw partials
    attn_mfma<<<dim3(64,2,4),256,0,stream>>>(wsb);
    // 5. split attn output for out-proj
    split_bf16<<<2048,256,0,stream>>>((const float*)(wsb+OFF_ATTN32),
                                      (u16*)(wsb+OFF_ATTN_HI), (u16*)(wsb+OFF_ATTN_LO));
    // 6. out-projection (MFMA) -> first output
    gemm_split<1><<<dim3(8,32,1),256,0,stream>>>(wsb, opb, out);
    // 7. aw mean over heads -> second output
    aw_reduce2<<<4096,256,0,stream>>>((const float*)(wsb+OFF_AW(0)),
                                      (const float*)(wsb+OFF_AW(1)), out + 4*MBY);
}

// Round 3
// 637.735 us; speedup vs baseline: 2.5676x; 1.0788x over previous
//
#include <hip/hip_runtime.h>

typedef __attribute__((ext_vector_type(8))) short s8v;
typedef __attribute__((ext_vector_type(4))) float f4v;
typedef unsigned short u16;

#define T_LEN 1024
#define B_SZ 4
#define H_NUM 16
#define D_DIM 64
#define E_DIM 1024

#define MBY ((size_t)1<<20)

// ---- workspace layout (bytes), total 128MB, phase-overlaid ----
// phase 1 (splits + QKV gemm): x splits at z*16MB; ipw 64/70MB; opw 76/78MB
// phase 2 (attention):         aw partials 0/16MB; v_t 32/40MB; attn hi/lo 48/56MB
// phase 3 (out-proj):          reads attn 48/56 + opw 76/78
#define OFF_X(z)     ((size_t)(z)*16*MBY)
#define OFF_AW(g)    ((size_t)(g)*16*MBY)
#define OFF_VT_HI    (32*MBY)
#define OFF_VT_LO    (40*MBY)
#define OFF_ATTN_HI  (48*MBY)
#define OFF_ATTN_LO  (56*MBY)
#define OFF_IPW_HI   (64*MBY)
#define OFF_IPW_LO   (70*MBY)
#define OFF_OPW_HI   (76*MBY)
#define OFF_OPW_LO   (78*MBY)
#define OFF_QKV(z)   ((80*MBY) + (size_t)(z)*16*MBY)   // hi; lo = +8MB

__device__ __forceinline__ u16 f2bf(float x){
    unsigned u = __float_as_uint(x);
    u += 0x7fffu + ((u>>16)&1u);          // RNE
    return (u16)(u>>16);
}
__device__ __forceinline__ float bf2f(u16 h){
    return __uint_as_float(((unsigned)h)<<16);
}
__device__ __forceinline__ void glds16(const void* g, void* l){
    __builtin_amdgcn_global_load_lds((const __attribute__((address_space(1))) unsigned*)g,
                                     (__attribute__((address_space(3))) unsigned*)l, 16, 0, 0);
}
#define MFMA_BF16(a,b,c) __builtin_amdgcn_mfma_f32_16x16x32_bf16((a),(b),(c),0,0,0)

// ---------------------------------------------------------------------------
// fp32 -> (hi, lo) bf16 split, 8 elems/thread
// ---------------------------------------------------------------------------
__global__ __launch_bounds__(256) void split_bf16(const float* __restrict__ src,
        u16* __restrict__ hi, u16* __restrict__ lo)
{
    size_t i = ((size_t)blockIdx.x*256 + threadIdx.x)*8;
    float4 a = *(const float4*)(src + i);
    float4 b = *(const float4*)(src + i + 4);
    float v[8] = {a.x,a.y,a.z,a.w,b.x,b.y,b.z,b.w};
    s8v hv, lv;
    #pragma unroll
    for (int j=0;j<8;++j){
        u16 h = f2bf(v[j]);
        hv[j] = (short)h;
        lv[j] = (short)f2bf(v[j] - bf2f(h));
    }
    *(s8v*)(hi+i) = hv;
    *(s8v*)(lo+i) = lv;
}

// ---------------------------------------------------------------------------
// Split-bf16 MFMA GEMM (as round 2; passed): C = A*W^T (+bias)*scale
// MODE 0: QKV (z selects), out = hi/lo bf16 head-major [bh][t][d]
// MODE 1: out-proj, out = fp32 [m][n]
// ---------------------------------------------------------------------------
template<int MODE>
__global__ __launch_bounds__(256) void gemm_split(char* __restrict__ wsb,
        const float* __restrict__ bias0, float* __restrict__ out32)
{
    __shared__ u16 Ah[4096], Al[4096], Bh[4096], Bl[4096];
    const int tid = threadIdx.x;
    const int wv = tid>>6, l = tid&63;
    const int lr = l&15, lg = l>>4;
    const int z = (MODE==0)? blockIdx.z : 0;

    const u16 *Ahi,*Alo,*Whi,*Wlo;
    const float* bias; float scale;
    u16 *outH = nullptr, *outL = nullptr;
    if (MODE==0){
        Ahi = (const u16*)(wsb + OFF_X(z));
        Alo = Ahi + 4*MBY;
        Whi = (const u16*)(wsb + OFF_IPW_HI) + (size_t)z*E_DIM*E_DIM;
        Wlo = (const u16*)(wsb + OFF_IPW_LO) + (size_t)z*E_DIM*E_DIM;
        bias = bias0 + z*E_DIM;
        scale = (z==0)? 0.125f : 1.0f;     // D^-0.5 baked into q
        outH = (u16*)(wsb + OFF_QKV(z));
        outL = outH + 4*MBY;
    } else {
        Ahi = (const u16*)(wsb + OFF_ATTN_HI);
        Alo = (const u16*)(wsb + OFF_ATTN_LO);
        Whi = (const u16*)(wsb + OFF_OPW_HI);
        Wlo = (const u16*)(wsb + OFF_OPW_LO);
        bias = bias0; scale = 1.0f;
    }

    const int m0 = blockIdx.y*128, n0 = blockIdx.x*128;

    f4v acc[4][4];
    #pragma unroll
    for (int i=0;i<4;++i)
        #pragma unroll
        for (int j=0;j<4;++j) acc[i][j] = (f4v){0.f,0.f,0.f,0.f};

    for (int k0=0; k0<E_DIM; k0+=32){
        #pragma unroll
        for (int i=0;i<2;++i){
            int ci  = i*4 + wv;
            int row = ci*16 + (l>>2);
            int u   = (l&3) ^ ((l>>2)&3);
            size_t aoff = (size_t)(m0+row)*E_DIM + k0 + u*8;
            size_t boff = (size_t)(n0+row)*E_DIM + k0 + u*8;
            glds16(Ahi+aoff, &Ah[ci*512]);
            glds16(Alo+aoff, &Al[ci*512]);
            glds16(Whi+boff, &Bh[ci*512]);
            glds16(Wlo+boff, &Bl[ci*512]);
        }
        __syncthreads();
        s8v ah[4],al[4],bh[4],bl[4];
        #pragma unroll
        for (int mi=0;mi<4;++mi){
            int row = (wv>>1)*64 + mi*16 + lr;
            int off = row*32 + ((lg ^ (row&3))<<3);
            ah[mi] = *(const s8v*)&Ah[off];
            al[mi] = *(const s8v*)&Al[off];
        }
        #pragma unroll
        for (int ni=0;ni<4;++ni){
            int row = (wv&1)*64 + ni*16 + lr;
            int off = row*32 + ((lg ^ (row&3))<<3);
            bh[ni] = *(const s8v*)&Bh[off];
            bl[ni] = *(const s8v*)&Bl[off];
        }
        #pragma unroll
        for (int mi=0;mi<4;++mi)
            #pragma unroll
            for (int ni=0;ni<4;++ni){
                acc[mi][ni] = MFMA_BF16(ah[mi], bh[ni], acc[mi][ni]);
                acc[mi][ni] = MFMA_BF16(ah[mi], bl[ni], acc[mi][ni]);
                acc[mi][ni] = MFMA_BF16(al[mi], bh[ni], acc[mi][ni]);
            }
        __syncthreads();
    }

    #pragma unroll
    for (int mi=0;mi<4;++mi){
        #pragma unroll
        for (int ni=0;ni<4;++ni){
            int n = n0 + (wv&1)*64 + ni*16 + lr;
            float bn = bias[n];
            #pragma unroll
            for (int r=0;r<4;++r){
                int m = m0 + (wv>>1)*64 + mi*16 + lg*4 + r;
                float val = (acc[mi][ni][r] + bn)*scale;
                if (MODE==0){
                    int t = m>>2, bb = m&3, hh2 = n>>6, dd = n&63;
                    size_t idx = ((size_t)(bb*H_NUM+hh2)*T_LEN + t)*D_DIM + dd;
                    u16 hb_ = f2bf(val);
                    outH[idx] = hb_;
                    outL[idx] = f2bf(val - bf2f(hb_));
                } else {
                    out32[(size_t)m*E_DIM + n] = val;
                }
            }
        }
    }
}

// ---------------------------------------------------------------------------
// v (head-major [bh][s][d], hi/lo bf16) -> v_t ([bh][d][s], hi/lo bf16)
// ---------------------------------------------------------------------------
__global__ __launch_bounds__(256) void transpose_v(char* __restrict__ wsb)
{
    __shared__ u16 Th[64][72], Tl[64][72];
    const int tid = threadIdx.x;
    const int bh  = blockIdx.y;
    const int s0  = blockIdx.x*64;
    const u16* vh = (const u16*)(wsb + OFF_QKV(2));
    const u16* vl = vh + 4*MBY;
    u16* th = (u16*)(wsb + OFF_VT_HI);
    u16* tl = (u16*)(wsb + OFF_VT_LO);

    #pragma unroll
    for (int it=0; it<2; ++it){
        int u = it*256 + tid;
        int s = u>>3, c8 = u&7;
        size_t off = ((size_t)bh*T_LEN + s0+s)*D_DIM + c8*8;
        s8v a  = *(const s8v*)&vh[off];
        s8v b_ = *(const s8v*)&vl[off];
        #pragma unroll
        for (int j=0;j<8;++j){
            Th[c8*8+j][s] = (u16)a[j];
            Tl[c8*8+j][s] = (u16)b_[j];
        }
    }
    __syncthreads();
    #pragma unroll
    for (int it=0; it<2; ++it){
        int u = it*256 + tid;
        int d = u>>3, sc = u&7;
        s8v rh = *(const s8v*)&Th[d][sc*8];
        s8v rl = *(const s8v*)&Tl[d][sc*8];
        size_t off = ((size_t)bh*D_DIM + d)*T_LEN + s0 + sc*8;
        *(s8v*)&th[off] = rh;
        *(s8v*)&tl[off] = rl;
    }
}

// ---------------------------------------------------------------------------
// MFMA attention, 512 thr = 8 waves. Block = (16 q-rows, hg of 8 heads, b).
// QK^T: wave wv owns s-slice wv*16 within each 128-chunk; S in 32 regs (p[8]).
// Softmax: per-wave (m,s) partials -> one LDS exchange -> scale (1 barrier).
// P (16 x 1024, hi/lo, XOR-swizzled) written ONCE to LDS; PV is a 48-MFMA
// barrier-free run per wave (waves split s-half x d-slice), cross-added via
// LDS once. 3 barriers/head. Writes attn as hi/lo bf16 (no split pass) and
// aw reg-accumulated over 8 heads -> 2 partial buffers.
// ---------------------------------------------------------------------------
__global__ __launch_bounds__(512,4) void attn_mfma(char* __restrict__ wsb)
{
    __shared__ u16 Ph[16384], Pl[16384];      // [16 rows][1024 s] swizzled
    __shared__ float Ored[16*68];
    __shared__ float redMS[16*16];            // [row][wv][2] = (m,s)

    const int tid = threadIdx.x;
    const int wv = tid>>6, l = tid&63, lr = l&15, lg = l>>4;
    const int sh = wv>>2, dq = wv&3;
    const int t0 = blockIdx.x*16;
    const int hg = blockIdx.y;                // 0..1
    const int b  = blockIdx.z;

    const u16* qhi = (const u16*)(wsb + OFF_QKV(0));
    const u16* qlo = qhi + 4*MBY;
    const u16* khi = (const u16*)(wsb + OFF_QKV(1));
    const u16* klo = khi + 4*MBY;
    const u16* vth = (const u16*)(wsb + OFF_VT_HI);
    const u16* vtl = (const u16*)(wsb + OFF_VT_LO);
    u16* attnH = (u16*)(wsb + OFF_ATTN_HI);
    u16* attnL = (u16*)(wsb + OFF_ATTN_LO);
    float* awb = (float*)(wsb + OFF_AW(hg)) + (size_t)b*T_LEN*T_LEN;

    f4v aw[8];
    #pragma unroll
    for (int c=0;c<8;++c) aw[c] = (f4v){0.f,0.f,0.f,0.f};

    for (int hh=0; hh<8; ++hh){
        const int h = hg*8 + hh;
        const size_t hb = (size_t)(b*H_NUM + h)*T_LEN*D_DIM;

        // Q A-frags: row = lr, k = kh*32 + lg*8 + j
        s8v qfh[2], qfl[2];
        #pragma unroll
        for (int kh=0;kh<2;++kh){
            size_t qo = hb + (size_t)(t0+lr)*D_DIM + kh*32 + lg*8;
            qfh[kh] = *(const s8v*)&qhi[qo];
            qfl[kh] = *(const s8v*)&qlo[qo];
        }

        // ---- QK^T: p[c2] = S[q=lg*4+r][s=c2*128+wv*16+lr] ----
        f4v p[8];
        const size_t kb = hb + (size_t)(wv*16+lr)*D_DIM + lg*8;
        #pragma unroll
        for (int c2=0;c2<8;++c2){
            f4v a = (f4v){0.f,0.f,0.f,0.f};
            #pragma unroll
            for (int kh=0;kh<2;++kh){
                size_t ko = kb + (size_t)c2*8192 + kh*32;
                s8v kfh = *(const s8v*)&khi[ko];
                s8v kfl = *(const s8v*)&klo[ko];
                a = MFMA_BF16(qfh[kh], kfh, a);
                a = MFMA_BF16(qfh[kh], kfl, a);
                a = MFMA_BF16(qfl[kh], kfh, a);
            }
            p[c2] = a;
        }

        // ---- softmax: per-wave max+sum, one LDS exchange ----
        float mw[4];
        #pragma unroll
        for (int r=0;r<4;++r){
            float m_ = p[0][r];
            #pragma unroll
            for (int c2=1;c2<8;++c2) m_ = fmaxf(m_, p[c2][r]);
            m_ = fmaxf(m_, __shfl_xor(m_,1));
            m_ = fmaxf(m_, __shfl_xor(m_,2));
            m_ = fmaxf(m_, __shfl_xor(m_,4));
            m_ = fmaxf(m_, __shfl_xor(m_,8));
            float sw = 0.f;
            #pragma unroll
            for (int c2=0;c2<8;++c2){
                float e = __expf(p[c2][r]-m_);
                p[c2][r] = e;
                sw += e;
            }
            sw += __shfl_xor(sw,1); sw += __shfl_xor(sw,2);
            sw += __shfl_xor(sw,4); sw += __shfl_xor(sw,8);
            mw[r] = m_;
            if (lr==0){
                redMS[(lg*4+r)*16 + wv*2]     = m_;
                redMS[(lg*4+r)*16 + wv*2 + 1] = sw;
            }
        }
        __syncthreads();
        float scl[4];
        #pragma unroll
        for (int r=0;r<4;++r){
            const float* rp = &redMS[(lg*4+r)*16];
            f4v x0 = *(const f4v*)&rp[0];
            f4v x1 = *(const f4v*)&rp[4];
            f4v x2 = *(const f4v*)&rp[8];
            f4v x3 = *(const f4v*)&rp[12];
            float M = fmaxf(fmaxf(fmaxf(x0[0],x0[2]), fmaxf(x1[0],x1[2])),
                            fmaxf(fmaxf(x2[0],x2[2]), fmaxf(x3[0],x3[2])));
            float S = x0[1]*__expf(x0[0]-M) + x0[3]*__expf(x0[2]-M)
                    + x1[1]*__expf(x1[0]-M) + x1[3]*__expf(x1[2]-M)
                    + x2[1]*__expf(x2[0]-M) + x2[3]*__expf(x2[2]-M)
                    + x3[1]*__expf(x3[0]-M) + x3[3]*__expf(x3[2]-M);
            scl[r] = __expf(mw[r]-M)/S;
        }

        // ---- scale, aw accumulate, write P (hi/lo, 16B-unit XOR swizzle) ----
        #pragma unroll
        for (int c2=0;c2<8;++c2){
            #pragma unroll
            for (int r=0;r<4;++r){
                float v = p[c2][r]*scl[r];
                aw[c2][r] += v;
                int row  = lg*4 + r;
                int colS = c2*128 + wv*16 + lr;
                int addr = row*1024 + (((colS>>3) ^ row)<<3) + (colS&7);
                u16 hb_ = f2bf(v);
                Ph[addr] = hb_;
                Pl[addr] = f2bf(v - bf2f(hb_));
            }
        }
        __syncthreads();

        // ---- PV: wave (sh,dq): s-half sh (16 ks steps), d-cols dq*16+lr ----
        f4v O0 = (f4v){0.f,0.f,0.f,0.f};
        f4v O1 = (f4v){0.f,0.f,0.f,0.f};
        const size_t vb = hb + (size_t)(dq*16+lr)*T_LEN + lg*8;
        __builtin_amdgcn_s_setprio(1);
        #pragma unroll
        for (int k2=0;k2<8;++k2){
            {
                int ks = sh*16 + k2*2;
                int pa = lr*1024 + (((ks*4+lg) ^ lr)<<3);
                s8v pah = *(const s8v*)&Ph[pa];
                s8v pal = *(const s8v*)&Pl[pa];
                size_t vo = vb + (size_t)ks*32;
                s8v vfh = *(const s8v*)&vth[vo];
                s8v vfl = *(const s8v*)&vtl[vo];
                O0 = MFMA_BF16(pah, vfh, O0);
                O0 = MFMA_BF16(pah, vfl, O0);
                O0 = MFMA_BF16(pal, vfh, O0);
            }
            {
                int ks = sh*16 + k2*2 + 1;
                int pa = lr*1024 + (((ks*4+lg) ^ lr)<<3);
                s8v pah = *(const s8v*)&Ph[pa];
                s8v pal = *(const s8v*)&Pl[pa];
                size_t vo = vb + (size_t)ks*32;
                s8v vfh = *(const s8v*)&vth[vo];
                s8v vfl = *(const s8v*)&vtl[vo];
                O1 = MFMA_BF16(pah, vfh, O1);
                O1 = MFMA_BF16(pah, vfl, O1);
                O1 = MFMA_BF16(pal, vfh, O1);
            }
        }
        __builtin_amdgcn_s_setprio(0);

        if (sh==1){
            #pragma unroll
            for (int r=0;r<4;++r)
                Ored[(lg*4+r)*68 + dq*16+lr] = O0[r]+O1[r];
        }
        __syncthreads();
        if (sh==0){
            #pragma unroll
            for (int r=0;r<4;++r){
                float val = O0[r]+O1[r] + Ored[(lg*4+r)*68 + dq*16+lr];
                int m = (t0 + lg*4 + r)*B_SZ + b;
                size_t oi = (size_t)m*E_DIM + h*D_DIM + dq*16 + lr;
                u16 hb_ = f2bf(val);
                attnH[oi] = hb_;
                attnL[oi] = f2bf(val - bf2f(hb_));
            }
        }
    }

    // ---- aw partial write ----
    #pragma unroll
    for (int c2=0;c2<8;++c2)
        #pragma unroll
        for (int r=0;r<4;++r){
            int t = t0 + lg*4 + r;
            awb[(size_t)t*T_LEN + c2*128 + wv*16 + lr] = aw[c2][r];
        }
}

// ---------------------------------------------------------------------------
// aw = (p0+p1)/16
// ---------------------------------------------------------------------------
__global__ __launch_bounds__(256) void aw_reduce2(const float* __restrict__ p0,
        const float* __restrict__ p1, float* __restrict__ out2)
{
    size_t i = ((size_t)blockIdx.x*256 + threadIdx.x)*4;
    float4 a = *(const float4*)(p0+i);
    float4 b = *(const float4*)(p1+i);
    float4 r;
    r.x = (a.x+b.x)*0.0625f;
    r.y = (a.y+b.y)*0.0625f;
    r.z = (a.z+b.z)*0.0625f;
    r.w = (a.w+b.w)*0.0625f;
    *(float4*)(out2+i) = r;
}

extern "C" void kernel_launch(void* const* d_in, const int* in_sizes, int n_in,
                              void* d_out, int out_size, void* d_ws, size_t ws_size,
                              hipStream_t stream) {
    const float* query = (const float*)d_in[0];
    const float* key   = (const float*)d_in[1];
    const float* value = (const float*)d_in[2];
    const float* ipw   = (const float*)d_in[3];
    const float* ipb   = (const float*)d_in[4];
    const float* opw   = (const float*)d_in[5];
    const float* opb   = (const float*)d_in[6];
    // d_in[7..11] (co_*/h_*) are dead: softmax over a size-1 axis == 1 exactly.

    char* wsb = (char*)d_ws;
    float* out = (float*)d_out;

    // 1. hi/lo splits of inputs + weights
    split_bf16<<<2048,256,0,stream>>>(query, (u16*)(wsb+OFF_X(0)), (u16*)(wsb+OFF_X(0))+4*MBY);
    split_bf16<<<2048,256,0,stream>>>(key,   (u16*)(wsb+OFF_X(1)), (u16*)(wsb+OFF_X(1))+4*MBY);
    split_bf16<<<2048,256,0,stream>>>(value, (u16*)(wsb+OFF_X(2)), (u16*)(wsb+OFF_X(2))+4*MBY);
    split_bf16<<<1536,256,0,stream>>>(ipw,   (u16*)(wsb+OFF_IPW_HI), (u16*)(wsb+OFF_IPW_LO));
    split_bf16<<< 512,256,0,stream>>>(opw,   (u16*)(wsb+OFF_OPW_HI), (u16*)(wsb+OFF_OPW_LO));
    // 2. QKV projection (MFMA), head-major hi/lo out (q pre-scaled)
    gemm_split<0><<<dim3(8,32,3),256,0,stream>>>(wsb, ipb, nullptr);
    // 3. V transpose to [bh][d][s]
    transpose_v<<<dim3(16,64),256,0,stream>>>(wsb);
    // 4. attention: attn hi/lo + aw partials
    attn_mfma<<<dim3(64,2,4),512,0,stream>>>(wsb);
    // 5. out-projection (MFMA) -> first output
    gemm_split<1><<<dim3(8,32,1),256,0,stream>>>(wsb, opb, out);
    // 6. aw mean over heads -> second output
    aw_reduce2<<<4096,256,0,stream>>>((const float*)(wsb+OFF_AW(0)),
                                      (const float*)(wsb+OFF_AW(1)), out + 4*MBY);
}

// Round 4
// 604.479 us; speedup vs baseline: 2.7089x; 1.0550x over previous
//
#include <hip/hip_runtime.h>

typedef __attribute__((ext_vector_type(8))) short s8v;
typedef __attribute__((ext_vector_type(4))) float f4v;
typedef __attribute__((ext_vector_type(4))) unsigned u32x4;
typedef unsigned short u16;

#define T_LEN 1024
#define B_SZ 4
#define H_NUM 16
#define D_DIM 64
#define E_DIM 1024

#define MBY ((size_t)1<<20)

// ---- workspace layout (bytes), total 128MB, phase-overlaid ----
#define OFF_X(z)     ((size_t)(z)*16*MBY)
#define OFF_VT_HI    (32*MBY)
#define OFF_VT_LO    (40*MBY)
#define OFF_ATTN_HI  (48*MBY)
#define OFF_ATTN_LO  (56*MBY)
#define OFF_IPW_HI   (64*MBY)
#define OFF_IPW_LO   (70*MBY)
#define OFF_OPW_HI   (76*MBY)
#define OFF_OPW_LO   (78*MBY)
#define OFF_QKV(z)   ((80*MBY) + (size_t)(z)*16*MBY)   // hi; lo = +8MB

__device__ __forceinline__ u16 f2bf(float x){
    unsigned u = __float_as_uint(x);
    u += 0x7fffu + ((u>>16)&1u);          // RNE
    return (u16)(u>>16);
}
__device__ __forceinline__ float bf2f(u16 h){
    return __uint_as_float(((unsigned)h)<<16);
}
__device__ __forceinline__ void glds16(const void* g, void* l){
    __builtin_amdgcn_global_load_lds((const __attribute__((address_space(1))) unsigned*)g,
                                     (__attribute__((address_space(3))) unsigned*)l, 16, 0, 0);
}
#define MFMA_BF16(a,b,c) __builtin_amdgcn_mfma_f32_16x16x32_bf16((a),(b),(c),0,0,0)
#define SCHED_WALL __builtin_amdgcn_sched_barrier(0)
#define VM_WAIT8 asm volatile("s_waitcnt vmcnt(8)" ::: "memory")
#define VM_WAIT0 asm volatile("s_waitcnt vmcnt(0)" ::: "memory")
#define LGKM0    asm volatile("s_waitcnt lgkmcnt(0)" ::: "memory")
#define BARRIER() do{ SCHED_WALL; LGKM0; __builtin_amdgcn_s_barrier(); SCHED_WALL; }while(0)

// ---------------------------------------------------------------------------
// fp32 -> (hi, lo) bf16 split, 8 elems/thread
// ---------------------------------------------------------------------------
__global__ __launch_bounds__(256) void split_bf16(const float* __restrict__ src,
        u16* __restrict__ hi, u16* __restrict__ lo)
{
    size_t i = ((size_t)blockIdx.x*256 + threadIdx.x)*8;
    float4 a = *(const float4*)(src + i);
    float4 b = *(const float4*)(src + i + 4);
    float v[8] = {a.x,a.y,a.z,a.w,b.x,b.y,b.z,b.w};
    s8v hv, lv;
    #pragma unroll
    for (int j=0;j<8;++j){
        u16 h = f2bf(v[j]);
        hv[j] = (short)h;
        lv[j] = (short)f2bf(v[j] - bf2f(h));
    }
    *(s8v*)(hi+i) = hv;
    *(s8v*)(lo+i) = lv;
}

// ---------------------------------------------------------------------------
// Split-bf16 MFMA GEMM (proven rounds 2-3): C = A*W^T (+bias)*scale
// ---------------------------------------------------------------------------
template<int MODE>
__global__ __launch_bounds__(256) void gemm_split(char* __restrict__ wsb,
        const float* __restrict__ bias0, float* __restrict__ out32)
{
    __shared__ u16 Ah[4096], Al[4096], Bh[4096], Bl[4096];
    const int tid = threadIdx.x;
    const int wv = tid>>6, l = tid&63;
    const int lr = l&15, lg = l>>4;
    const int z = (MODE==0)? blockIdx.z : 0;

    const u16 *Ahi,*Alo,*Whi,*Wlo;
    const float* bias; float scale;
    u16 *outH = nullptr, *outL = nullptr;
    if (MODE==0){
        Ahi = (const u16*)(wsb + OFF_X(z));
        Alo = Ahi + 4*MBY;
        Whi = (const u16*)(wsb + OFF_IPW_HI) + (size_t)z*E_DIM*E_DIM;
        Wlo = (const u16*)(wsb + OFF_IPW_LO) + (size_t)z*E_DIM*E_DIM;
        bias = bias0 + z*E_DIM;
        scale = (z==0)? 0.125f : 1.0f;     // D^-0.5 baked into q
        outH = (u16*)(wsb + OFF_QKV(z));
        outL = outH + 4*MBY;
    } else {
        Ahi = (const u16*)(wsb + OFF_ATTN_HI);
        Alo = (const u16*)(wsb + OFF_ATTN_LO);
        Whi = (const u16*)(wsb + OFF_OPW_HI);
        Wlo = (const u16*)(wsb + OFF_OPW_LO);
        bias = bias0; scale = 1.0f;
    }

    const int m0 = blockIdx.y*128, n0 = blockIdx.x*128;

    f4v acc[4][4];
    #pragma unroll
    for (int i=0;i<4;++i)
        #pragma unroll
        for (int j=0;j<4;++j) acc[i][j] = (f4v){0.f,0.f,0.f,0.f};

    for (int k0=0; k0<E_DIM; k0+=32){
        #pragma unroll
        for (int i=0;i<2;++i){
            int ci  = i*4 + wv;
            int row = ci*16 + (l>>2);
            int u   = (l&3) ^ ((l>>2)&3);
            size_t aoff = (size_t)(m0+row)*E_DIM + k0 + u*8;
            size_t boff = (size_t)(n0+row)*E_DIM + k0 + u*8;
            glds16(Ahi+aoff, &Ah[ci*512]);
            glds16(Alo+aoff, &Al[ci*512]);
            glds16(Whi+boff, &Bh[ci*512]);
            glds16(Wlo+boff, &Bl[ci*512]);
        }
        __syncthreads();
        s8v ah[4],al[4],bh[4],bl[4];
        #pragma unroll
        for (int mi=0;mi<4;++mi){
            int row = (wv>>1)*64 + mi*16 + lr;
            int off = row*32 + ((lg ^ (row&3))<<3);
            ah[mi] = *(const s8v*)&Ah[off];
            al[mi] = *(const s8v*)&Al[off];
        }
        #pragma unroll
        for (int ni=0;ni<4;++ni){
            int row = (wv&1)*64 + ni*16 + lr;
            int off = row*32 + ((lg ^ (row&3))<<3);
            bh[ni] = *(const s8v*)&Bh[off];
            bl[ni] = *(const s8v*)&Bl[off];
        }
        #pragma unroll
        for (int mi=0;mi<4;++mi)
            #pragma unroll
            for (int ni=0;ni<4;++ni){
                acc[mi][ni] = MFMA_BF16(ah[mi], bh[ni], acc[mi][ni]);
                acc[mi][ni] = MFMA_BF16(ah[mi], bl[ni], acc[mi][ni]);
                acc[mi][ni] = MFMA_BF16(al[mi], bh[ni], acc[mi][ni]);
            }
        __syncthreads();
    }

    #pragma unroll
    for (int mi=0;mi<4;++mi){
        #pragma unroll
        for (int ni=0;ni<4;++ni){
            int n = n0 + (wv&1)*64 + ni*16 + lr;
            float bn = bias[n];
            #pragma unroll
            for (int r=0;r<4;++r){
                int m = m0 + (wv>>1)*64 + mi*16 + lg*4 + r;
                float val = (acc[mi][ni][r] + bn)*scale;
                if (MODE==0){
                    int t = m>>2, bb = m&3, hh2 = n>>6, dd = n&63;
                    size_t idx = ((size_t)(bb*H_NUM+hh2)*T_LEN + t)*D_DIM + dd;
                    u16 hb_ = f2bf(val);
                    outH[idx] = hb_;
                    outL[idx] = f2bf(val - bf2f(hb_));
                } else {
                    out32[(size_t)m*E_DIM + n] = val;
                }
            }
        }
    }
}

// ---------------------------------------------------------------------------
// v (head-major [bh][s][d], hi/lo bf16) -> v_t ([bh][d][s], hi/lo bf16)
// ---------------------------------------------------------------------------
__global__ __launch_bounds__(256) void transpose_v(char* __restrict__ wsb)
{
    __shared__ u16 Th[64][72], Tl[64][72];
    const int tid = threadIdx.x;
    const int bh  = blockIdx.y;
    const int s0  = blockIdx.x*64;
    const u16* vh = (const u16*)(wsb + OFF_QKV(2));
    const u16* vl = vh + 4*MBY;
    u16* th = (u16*)(wsb + OFF_VT_HI);
    u16* tl = (u16*)(wsb + OFF_VT_LO);

    #pragma unroll
    for (int it=0; it<2; ++it){
        int u = it*256 + tid;
        int s = u>>3, c8 = u&7;
        size_t off = ((size_t)bh*T_LEN + s0+s)*D_DIM + c8*8;
        s8v a  = *(const s8v*)&vh[off];
        s8v b_ = *(const s8v*)&vl[off];
        #pragma unroll
        for (int j=0;j<8;++j){
            Th[c8*8+j][s] = (u16)a[j];
            Tl[c8*8+j][s] = (u16)b_[j];
        }
    }
    __syncthreads();
    #pragma unroll
    for (int it=0; it<2; ++it){
        int u = it*256 + tid;
        int d = u>>3, sc = u&7;
        s8v rh = *(const s8v*)&Th[d][sc*8];
        s8v rl = *(const s8v*)&Tl[d][sc*8];
        size_t off = ((size_t)bh*D_DIM + d)*T_LEN + s0 + sc*8;
        *(s8v*)&th[off] = rh;
        *(s8v*)&tl[off] = rl;
    }
}

// ---------------------------------------------------------------------------
// Attention, 512 thr = 8 waves, grid (64 t-tiles, 4 b) = 256 blocks = 1/CU.
// Block covers 16 q-rows x ALL 16 heads; wave wv owns s in [wv*128, wv*128+128).
// Swapped QK^T (mfma(K,Q)) -> q is lane-local (q = lane&15) -> PV A-frags via
// tiny intra-wave LDS exchange. K/V staged per-wave via async global_load_lds
// into private double-buffered 8KB slots with counted vmcnt(8) waits -- the
// main loops have NO barriers. 2 raw barriers/head (softmax exchange + O
// reduce via ds_add_f32). aw accumulated over all 16 heads in regs, written
// directly to the final output (no partial buffers / reduce pass).
// ---------------------------------------------------------------------------
__global__ __launch_bounds__(512,2) void attn_mfma(char* __restrict__ wsb,
        float* __restrict__ aw_out)
{
    __shared__ u16 STG[8][2][4096];       // per-wave dbuf slots, 8KB each
    __shared__ unsigned PEX[8][512];      // per-wave P exchange, 2KB each
    __shared__ float ORED[2][1024];       // O cross-wave reduce (ping-pong)
    __shared__ float REDMS[16][16];       // softmax (m,s) per q-row per wave

    const int tid = threadIdx.x;
    const int wv = tid>>6, l = tid&63, lr = l&15, lg = l>>4;
    const int t0 = blockIdx.x*16;
    const int b  = blockIdx.y;
    const int sb = wv*128;

    const u16* qhi = (const u16*)(wsb + OFF_QKV(0));
    const u16* qlo = qhi + 4*MBY;
    const u16* khi = (const u16*)(wsb + OFF_QKV(1));
    const u16* klo = khi + 4*MBY;
    const u16* vth = (const u16*)(wsb + OFF_VT_HI);
    const u16* vtl = (const u16*)(wsb + OFF_VT_LO);
    u16* attnH = (u16*)(wsb + OFF_ATTN_HI);
    u16* attnL = (u16*)(wsb + OFF_ATTN_LO);

    // zero O-reduce buffers (ordered before first use by first BARRIER)
    *(f4v*)&((float*)ORED)[tid*4] = (f4v){0.f,0.f,0.f,0.f};

    f4v aw[4][2];
    #pragma unroll
    for (int bk=0;bk<4;++bk){ aw[bk][0]=(f4v){0,0,0,0}; aw[bk][1]=(f4v){0,0,0,0}; }

    u16* sA = &STG[wv][0][0];
    u16* sB = &STG[wv][1][0];
    unsigned* ex = &PEX[wv][0];

    // stage helpers (dest base wave-uniform; source pre-swizzled per lane)
    auto stageK = [&](u16* slot, size_t hb_, int sbase){
        #pragma unroll
        for (int i=0;i<4;++i){
            int sl = i*8 + (l>>3);
            int gu = (l&7) ^ (sl&7);
            size_t src = hb_ + (size_t)(sbase+sl)*64 + gu*8;
            glds16(khi + src, slot + i*512);
            glds16(klo + src, slot + 2048 + i*512);
        }
    };
    auto stageV = [&](u16* slot, size_t vb_, int sbase){
        #pragma unroll
        for (int i=0;i<4;++i){
            int d = i*16 + (l>>2);
            int gu = ((l&3) + (d>>2)) & 3;
            size_t src = vb_ + (size_t)d*1024 + sbase + gu*8;
            glds16(vth + src, slot + i*512);
            glds16(vtl + src, slot + 2048 + i*512);
        }
    };

    // prologue: stage head 0's first two K blocks
    {
        size_t hb0 = (size_t)(b*H_NUM)*65536;
        stageK(sA, hb0, sb);
        stageK(sB, hb0, sb+32);
    }

    for (int hh=0; hh<16; ++hh){
        const size_t hb  = (size_t)(b*H_NUM + hh)*65536;
        const size_t hbn = (size_t)(b*H_NUM + ((hh+1)&15))*65536;

        // Q fragments (B-operand layout == row-major 16B loads)
        s8v qfh[2], qfl[2];
        #pragma unroll
        for (int kh=0;kh<2;++kh){
            size_t qo = hb + (size_t)(t0+lr)*64 + kh*32 + lg*8;
            qfh[kh] = *(const s8v*)&qhi[qo];
            qfl[kh] = *(const s8v*)&qlo[qo];
        }

        // ---- QK^T (swapped): p[bk][t][r] = S[q=lr][s = sb+bk*32+t*16+lg*4+r]
        f4v p[4][2];
        #pragma unroll
        for (int bk=0;bk<4;++bk){
            SCHED_WALL;
            if (bk==1) stageK(sA, hb, sb+64);
            else if (bk==2) stageK(sB, hb, sb+96);
            else if (bk==3) stageV(sA, hb, sb);
            VM_WAIT8; SCHED_WALL;
            const u16* sp = (bk&1)? sB : sA;
            #pragma unroll
            for (int t=0;t<2;++t){
                int sl = t*16 + lr;
                int sw = sl&7;
                s8v k0h = *(const s8v*)&sp[sl*64 + ((lg  ^sw)<<3)];
                s8v k1h = *(const s8v*)&sp[sl*64 + (((4+lg)^sw)<<3)];
                s8v k0l = *(const s8v*)&sp[2048 + sl*64 + ((lg  ^sw)<<3)];
                s8v k1l = *(const s8v*)&sp[2048 + sl*64 + (((4+lg)^sw)<<3)];
                f4v a1 = (f4v){0,0,0,0}, a2 = (f4v){0,0,0,0};
                a1 = MFMA_BF16(k0h, qfh[0], a1);
                a1 = MFMA_BF16(k1h, qfh[1], a1);
                a2 = MFMA_BF16(k0h, qfl[0], a2);
                a2 = MFMA_BF16(k1h, qfl[1], a2);
                a2 = MFMA_BF16(k0l, qfh[0], a2);
                a2 = MFMA_BF16(k1l, qfh[1], a2);
                p[bk][t] = a1 + a2;
            }
        }
        SCHED_WALL;
        stageV(sB, hb, sb+32);

        // ---- softmax: in-lane (32 vals of row q=lr) + xor over lg + wave exch
        float mw = p[0][0][0];
        #pragma unroll
        for (int bk=0;bk<4;++bk)
            #pragma unroll
            for (int t=0;t<2;++t)
                #pragma unroll
                for (int r=0;r<4;++r) mw = fmaxf(mw, p[bk][t][r]);
        mw = fmaxf(mw, __shfl_xor(mw, 16));
        mw = fmaxf(mw, __shfl_xor(mw, 32));
        float sw_ = 0.f;
        #pragma unroll
        for (int bk=0;bk<4;++bk)
            #pragma unroll
            for (int t=0;t<2;++t)
                #pragma unroll
                for (int r=0;r<4;++r){
                    float e = __expf(p[bk][t][r] - mw);
                    p[bk][t][r] = e;
                    sw_ += e;
                }
        sw_ += __shfl_xor(sw_, 16);
        sw_ += __shfl_xor(sw_, 32);
        if (lg==0){ REDMS[lr][wv*2] = mw; REDMS[lr][wv*2+1] = sw_; }
        BARRIER();
        float scl;
        {
            f4v x0 = *(const f4v*)&REDMS[lr][0];
            f4v x1 = *(const f4v*)&REDMS[lr][4];
            f4v x2 = *(const f4v*)&REDMS[lr][8];
            f4v x3 = *(const f4v*)&REDMS[lr][12];
            float M = fmaxf(fmaxf(fmaxf(x0[0],x0[2]), fmaxf(x1[0],x1[2])),
                            fmaxf(fmaxf(x2[0],x2[2]), fmaxf(x3[0],x3[2])));
            float S = x0[1]*__expf(x0[0]-M) + x0[3]*__expf(x0[2]-M)
                    + x1[1]*__expf(x1[0]-M) + x1[3]*__expf(x1[2]-M)
                    + x2[1]*__expf(x2[0]-M) + x2[3]*__expf(x2[2]-M)
                    + x3[1]*__expf(x3[0]-M) + x3[3]*__expf(x3[2]-M);
            scl = __expf(mw - M) / S;
        }

        // ---- finalize P: scale, aw accumulate, pack hi/lo bf16 pairs
        u32x4 pk[4][2];
        #pragma unroll
        for (int bk=0;bk<4;++bk)
            #pragma unroll
            for (int t=0;t<2;++t){
                float v0 = p[bk][t][0]*scl, v1 = p[bk][t][1]*scl;
                float v2 = p[bk][t][2]*scl, v3 = p[bk][t][3]*scl;
                aw[bk][t][0] += v0; aw[bk][t][1] += v1;
                aw[bk][t][2] += v2; aw[bk][t][3] += v3;
                u16 h0=f2bf(v0), h1=f2bf(v1), h2=f2bf(v2), h3=f2bf(v3);
                u16 l0=f2bf(v0-bf2f(h0)), l1=f2bf(v1-bf2f(h1));
                u16 l2=f2bf(v2-bf2f(h2)), l3=f2bf(v3-bf2f(h3));
                pk[bk][t] = (u32x4){ (unsigned)h0 | ((unsigned)h1<<16),
                                     (unsigned)h2 | ((unsigned)h3<<16),
                                     (unsigned)l0 | ((unsigned)l1<<16),
                                     (unsigned)l2 | ((unsigned)l3<<16) };
            }

        // ---- PV: O[q][d] += P * V over wave's 128 s
        f4v Oa[4], Ob[4];
        #pragma unroll
        for (int ds=0;ds<4;++ds){ Oa[ds]=(f4v){0,0,0,0}; Ob[ds]=(f4v){0,0,0,0}; }
        #pragma unroll
        for (int bk=0;bk<4;++bk){
            SCHED_WALL;
            if (bk==1) stageV(sA, hb, sb+64);
            else if (bk==2) stageV(sB, hb, sb+96);
            else if (bk==3) stageK(sA, hbn, sb);       // next head prefetch
            VM_WAIT8; SCHED_WALL;
            // intra-wave P exchange -> A-frag layout
            *(u32x4*)&ex[l*8]   = pk[bk][0];
            *(u32x4*)&ex[l*8+4] = pk[bk][1];
            int srcA = ((lg&1)*32 + lr)*8 + (lg>>1)*4;
            u32x4 rdA = *(const u32x4*)&ex[srcA];
            u32x4 rdB = *(const u32x4*)&ex[srcA + 128];
            union Wu { unsigned u[4]; s8v s; } uh, ul;
            uh.u[0]=rdA[0]; uh.u[1]=rdA[1]; uh.u[2]=rdB[0]; uh.u[3]=rdB[1];
            ul.u[0]=rdA[2]; ul.u[1]=rdA[3]; ul.u[2]=rdB[2]; ul.u[3]=rdB[3];
            const u16* vp = (bk&1)? sB : sA;
            #pragma unroll
            for (int ds=0;ds<4;++ds){
                int d = ds*16 + lr;
                int uu = (lg - (d>>2)) & 3;
                s8v vh_ = *(const s8v*)&vp[d*32 + (uu<<3)];
                s8v vl_ = *(const s8v*)&vp[2048 + d*32 + (uu<<3)];
                Oa[ds] = MFMA_BF16(uh.s, vh_, Oa[ds]);
                Ob[ds] = MFMA_BF16(uh.s, vl_, Ob[ds]);
                Ob[ds] = MFMA_BF16(ul.s, vh_, Ob[ds]);
            }
        }
        SCHED_WALL;
        stageK(sB, hbn, sb+32);                        // next head prefetch

        // ---- cross-wave O reduce + attn write
        #pragma unroll
        for (int ds=0;ds<4;++ds)
            #pragma unroll
            for (int r=0;r<4;++r)
                atomicAdd(&ORED[hh&1][(lg*4+r)*64 + ds*16 + lr], Oa[ds][r]+Ob[ds][r]);
        BARRIER();
        {
            int e = tid*2;
            float v0 = ORED[hh&1][e], v1 = ORED[hh&1][e+1];
            ORED[hh&1][e] = 0.f; ORED[hh&1][e+1] = 0.f;   // re-arm for hh+2
            int qq = e>>6, dd = e&63;
            size_t oi = ((size_t)((t0+qq)*B_SZ + b))*E_DIM + hh*64 + dd;
            u16 h0 = f2bf(v0), h1 = f2bf(v1);
            *(unsigned*)&attnH[oi] = (unsigned)h0 | ((unsigned)h1<<16);
            u16 lo0 = f2bf(v0 - bf2f(h0)), lo1 = f2bf(v1 - bf2f(h1));
            *(unsigned*)&attnL[oi] = (unsigned)lo0 | ((unsigned)lo1<<16);
        }
    }

    // ---- aw flush: per-wave transpose via own staging slot, /16, coalesced
    VM_WAIT0; SCHED_WALL;
    float* awt = (float*)&STG[wv][0][0];               // 8KB region
    #pragma unroll
    for (int bk=0;bk<4;++bk)
        #pragma unroll
        for (int t=0;t<2;++t)
            *(f4v*)&awt[lr*128 + bk*32 + t*16 + lg*4] = aw[bk][t]*0.0625f;
    #pragma unroll
    for (int j=0;j<8;++j){
        int idx = j*256 + l*4;
        f4v vv = *(const f4v*)&awt[idx];
        *(f4v*)&aw_out[(size_t)b*(T_LEN*T_LEN) + (size_t)(t0+(idx>>7))*T_LEN
                       + sb + (idx&127)] = vv;
    }
}

extern "C" void kernel_launch(void* const* d_in, const int* in_sizes, int n_in,
                              void* d_out, int out_size, void* d_ws, size_t ws_size,
                              hipStream_t stream) {
    const float* query = (const float*)d_in[0];
    const float* key   = (const float*)d_in[1];
    const float* value = (const float*)d_in[2];
    const float* ipw   = (const float*)d_in[3];
    const float* ipb   = (const float*)d_in[4];
    const float* opw   = (const float*)d_in[5];
    const float* opb   = (const float*)d_in[6];
    // d_in[7..11] (co_*/h_*) are dead: softmax over a size-1 axis == 1 exactly.

    char* wsb = (char*)d_ws;
    float* out = (float*)d_out;

    // 1. hi/lo splits of inputs + weights
    split_bf16<<<2048,256,0,stream>>>(query, (u16*)(wsb+OFF_X(0)), (u16*)(wsb+OFF_X(0))+4*MBY);
    split_bf16<<<2048,256,0,stream>>>(key,   (u16*)(wsb+OFF_X(1)), (u16*)(wsb+OFF_X(1))+4*MBY);
    split_bf16<<<2048,256,0,stream>>>(value, (u16*)(wsb+OFF_X(2)), (u16*)(wsb+OFF_X(2))+4*MBY);
    split_bf16<<<1536,256,0,stream>>>(ipw,   (u16*)(wsb+OFF_IPW_HI), (u16*)(wsb+OFF_IPW_LO));
    split_bf16<<< 512,256,0,stream>>>(opw,   (u16*)(wsb+OFF_OPW_HI), (u16*)(wsb+OFF_OPW_LO));
    // 2. QKV projection (MFMA), head-major hi/lo out (q pre-scaled)
    gemm_split<0><<<dim3(8,32,3),256,0,stream>>>(wsb, ipb, nullptr);
    // 3. V transpose to [bh][d][s]
    transpose_v<<<dim3(16,64),256,0,stream>>>(wsb);
    // 4. attention: attn hi/lo + aw (final) directly
    attn_mfma<<<dim3(64,4),512,0,stream>>>(wsb, out + (size_t)B_SZ*T_LEN*E_DIM/1);
    // 5. out-projection (MFMA) -> first output
    gemm_split<1><<<dim3(8,32,1),256,0,stream>>>(wsb, opb, out);
}